// Round 6
// baseline (376.060 us; speedup 1.0000x reference)
//
#include <hip/hip_runtime.h>
#include <math.h>

#define BB 32
#define SS 4096
#define DIN 1024
#define DOUT 1024
#define NCHUNK 32                          // s-chunks per batch row
#define ROWS_PER_BLOCK (SS / NCHUNK)       // 128
#define ROWS_PER_WAVE (ROWS_PER_BLOCK / 4) // 32
#define PART_STRIDE 1040                   // floats: [0]=m, [1]=l, [16..1039]=ctx[1024]
#define THR 25.0f                          // defer-max rescale threshold (e^25 safe in f32)

typedef float vf4 __attribute__((ext_vector_type(4)));

__device__ inline vf4 ntload4(const float* p) {
  return __builtin_nontemporal_load((const vf4*)p);
}

// ---------------- kernel 1: x[b,o] = sum_i input[b,i] * W[o,i] ----------------
// 1024 blocks (b, ochunk), 8 o-dots per wave, fully parallel. Block 0 also
// zeroes the per-batch completion counters used by pass_kernel's fused merge.
__global__ __launch_bounds__(256) void proj_kernel(const float* __restrict__ input,
                                                   const float* __restrict__ W,
                                                   float* __restrict__ x,
                                                   int* __restrict__ cnt) {
  const int b = blockIdx.x >> 5;        // 32 o-chunks per b
  const int ochunk = blockIdx.x & 31;
  __shared__ float inp[DIN];
  const int t = threadIdx.x;
  if (blockIdx.x == 0 && t < BB) cnt[t] = 0;
  ((vf4*)inp)[t] = ((const vf4*)(input + (size_t)b * DIN))[t];
  __syncthreads();
  const int wave = t >> 6, lane = t & 63;
#pragma unroll
  for (int j = 0; j < 8; ++j) {
    const int o = ochunk * 32 + wave * 8 + j;
    const vf4* wrow = (const vf4*)(W + (size_t)o * DIN);
    vf4 prod = (vf4)0.f;
#pragma unroll
    for (int k = 0; k < 4; ++k) prod += wrow[lane + 64 * k] * ((const vf4*)inp)[lane + 64 * k];
    float sum = prod.x + prod.y + prod.z + prod.w;
#pragma unroll
    for (int off = 32; off; off >>= 1) sum += __shfl_down(sum, off);
    if (lane == 0) x[(size_t)b * DOUT + o] = sum;
  }
}

// ---- kernel 2: single pass over source_hids: scores + online softmax + ctx ----
// Last-finishing block per batch also performs the final merge (fused combine).
__global__ __launch_bounds__(256) void pass_kernel(const float* __restrict__ hids,
                                                   const float* __restrict__ seg,
                                                   const float* __restrict__ x,
                                                   float* __restrict__ raw_scores,   // d_out attn region
                                                   float* __restrict__ out_ctx,
                                                   float* __restrict__ partials,
                                                   int* __restrict__ cnt) {
  const int b = blockIdx.x >> 5;        // 32 chunks per b
  const int chunk = blockIdx.x & 31;
  const int t = threadIdx.x;
  __shared__ float xs[DOUT];
  __shared__ float buf[4][DOUT];
  __shared__ float sbuf[ROWS_PER_BLOCK];
  __shared__ float wstat[8];            // M[0..3], l[4..7]
  __shared__ float sm[NCHUNK], sl[NCHUNK];
  __shared__ int isLast;
  ((vf4*)xs)[t] = ((const vf4*)(x + (size_t)b * DOUT))[t];
  __syncthreads();
  const int wave = t >> 6, lane = t & 63;
  vf4 xv[4];
#pragma unroll
  for (int k = 0; k < 4; ++k) xv[k] = ((const vf4*)xs)[lane + 64 * k];

  const int s0 = chunk * ROWS_PER_BLOCK + wave * ROWS_PER_WAVE;
  const float* base = hids + ((size_t)b * SS + s0) * (size_t)DOUT;
  const float* segb = seg + (size_t)b * SS + s0;

  // all 32 seg values for this wave in one coalesced load (lane&31 avoids OOB)
  const float segv = segb[lane & 31];

  // ---- 2-row pipeline, 2 rows ahead (4 rows / 16KB in flight per wave) ----
  vf4 h0[4], h1[4], n0[4], n1[4];
#pragma unroll
  for (int k = 0; k < 4; ++k) h0[k] = ntload4(base + (lane + 64 * k) * 4);
#pragma unroll
  for (int k = 0; k < 4; ++k) h1[k] = ntload4(base + DOUT + (lane + 64 * k) * 4);
#pragma unroll
  for (int k = 0; k < 4; ++k) n0[k] = ntload4(base + 2 * DOUT + (lane + 64 * k) * 4);
#pragma unroll
  for (int k = 0; k < 4; ++k) n1[k] = ntload4(base + 3 * DOUT + (lane + 64 * k) * 4);

  // prologue: row 0 sets reference M; row 1 defer-max update
  vf4 prod0 = h0[0] * xv[0] + h0[1] * xv[1] + h0[2] * xv[2] + h0[3] * xv[3];
  float dot0 = prod0.x + prod0.y + prod0.z + prod0.w;
  vf4 prod1 = h1[0] * xv[0] + h1[1] * xv[1] + h1[2] * xv[2] + h1[3] * xv[3];
  float dot1 = prod1.x + prod1.y + prod1.z + prod1.w;
#pragma unroll
  for (int off = 32; off; off >>= 1) { dot0 += __shfl_xor(dot0, off); dot1 += __shfl_xor(dot1, off); }

  float M = dot0 - 100.f * (1.f - __shfl(segv, 0));
  float l = 1.f;
  vf4 acc[4];
#pragma unroll
  for (int k = 0; k < 4; ++k) acc[k] = h0[k];
  if (lane == 0) sbuf[wave * ROWS_PER_WAVE] = M;

  {
    const float score = dot1 - 100.f * (1.f - __shfl(segv, 1));
    if (lane == 0) sbuf[wave * ROWS_PER_WAVE + 1] = score;
    float p;
    if (__builtin_expect(score > M + THR, 0)) {
      const float corr = __expf(M - score);
      l *= corr;
#pragma unroll
      for (int k = 0; k < 4; ++k) acc[k] *= corr;
      M = score; p = 1.f;
    } else p = __expf(score - M);
    l += p;
#pragma unroll
    for (int k = 0; k < 4; ++k) acc[k] += p * h1[k];
  }

  // steady state: iteration rr processes rows 2rr, 2rr+1; prefetches 2rr+2, 2rr+3
#pragma unroll 2
  for (int rr = 1; rr < ROWS_PER_WAVE / 2; ++rr) {
#pragma unroll
    for (int k = 0; k < 4; ++k) { h0[k] = n0[k]; h1[k] = n1[k]; }
    if (rr + 1 < ROWS_PER_WAVE / 2) {
      const float* pb0 = base + (size_t)(2 * rr + 2) * DOUT;
      const float* pb1 = base + (size_t)(2 * rr + 3) * DOUT;
#pragma unroll
      for (int k = 0; k < 4; ++k) n0[k] = ntload4(pb0 + (lane + 64 * k) * 4);
#pragma unroll
      for (int k = 0; k < 4; ++k) n1[k] = ntload4(pb1 + (lane + 64 * k) * 4);
    }

    vf4 pa = h0[0] * xv[0] + h0[1] * xv[1] + h0[2] * xv[2] + h0[3] * xv[3];
    vf4 pbv = h1[0] * xv[0] + h1[1] * xv[1] + h1[2] * xv[2] + h1[3] * xv[3];
    float da = pa.x + pa.y + pa.z + pa.w;
    float db = pbv.x + pbv.y + pbv.z + pbv.w;
#pragma unroll
    for (int off = 32; off; off >>= 1) { da += __shfl_xor(da, off); db += __shfl_xor(db, off); }

    const float sa = da - 100.f * (1.f - __shfl(segv, 2 * rr));
    const float sb = db - 100.f * (1.f - __shfl(segv, 2 * rr + 1));
    if (lane == 0) {
      sbuf[wave * ROWS_PER_WAVE + 2 * rr] = sa;
      sbuf[wave * ROWS_PER_WAVE + 2 * rr + 1] = sb;
    }

    float p;
    if (__builtin_expect(sa > M + THR, 0)) {
      const float corr = __expf(M - sa);
      l *= corr;
#pragma unroll
      for (int k = 0; k < 4; ++k) acc[k] *= corr;
      M = sa; p = 1.f;
    } else p = __expf(sa - M);
    l += p;
#pragma unroll
    for (int k = 0; k < 4; ++k) acc[k] += p * h0[k];

    if (__builtin_expect(sb > M + THR, 0)) {
      const float corr = __expf(M - sb);
      l *= corr;
#pragma unroll
      for (int k = 0; k < 4; ++k) acc[k] *= corr;
      M = sb; p = 1.f;
    } else p = __expf(sb - M);
    l += p;
#pragma unroll
    for (int k = 0; k < 4; ++k) acc[k] += p * h1[k];
  }

  // ---- block-level combine of the 4 waves ----
  if (lane == 0) { wstat[wave] = M; wstat[4 + wave] = l; }
  __syncthreads();
  const float mb = fmaxf(fmaxf(wstat[0], wstat[1]), fmaxf(wstat[2], wstat[3]));
  const float scale = __expf(M - mb);     // per-wave scale to common reference
#pragma unroll
  for (int k = 0; k < 4; ++k)
    ((vf4*)buf[wave])[lane + 64 * k] = acc[k] * scale;
  __syncthreads();

  // coalesced raw-score write (one block: 128 contiguous floats)
  if (t < ROWS_PER_BLOCK)
    raw_scores[(size_t)b * SS + chunk * ROWS_PER_BLOCK + t] = sbuf[t];

  float* part = partials + ((size_t)b * NCHUNK + chunk) * PART_STRIDE;
  vf4 v0 = ((const vf4*)buf[0])[t];
  vf4 v1 = ((const vf4*)buf[1])[t];
  vf4 v2 = ((const vf4*)buf[2])[t];
  vf4 v3 = ((const vf4*)buf[3])[t];
  ((vf4*)(part + 16))[t] = (v0 + v1) + (v2 + v3);
  if (t == 0) {
    const float lb = wstat[4] * __expf(wstat[0] - mb) + wstat[5] * __expf(wstat[1] - mb) +
                     wstat[6] * __expf(wstat[2] - mb) + wstat[7] * __expf(wstat[3] - mb);
    part[0] = mb;
    part[1] = lb;
  }

  // ---- decoupled last-block merge (release: fence + device-scope atomic) ----
  __threadfence();
  if (t == 0) isLast = (atomicAdd(&cnt[b], 1) == NCHUNK - 1);
  __syncthreads();
  if (isLast) {
    __threadfence();   // acquire side
    const float* pball = partials + (size_t)b * NCHUNK * PART_STRIDE;
    if (t < NCHUNK) {
      sm[t] = pball[(size_t)t * PART_STRIDE];
      sl[t] = pball[(size_t)t * PART_STRIDE + 1];
    }
    __syncthreads();
    float m2 = -INFINITY;
#pragma unroll
    for (int j = 0; j < NCHUNK; ++j) m2 = fmaxf(m2, sm[j]);
    float l2 = 0.f;
#pragma unroll
    for (int j = 0; j < NCHUNK; ++j) l2 += sl[j] * __expf(sm[j] - m2);
    const float inv_l = 1.f / l2;

    vf4 c = (vf4)0.f;
#pragma unroll 8
    for (int j = 0; j < NCHUNK; ++j)
      c += __expf(sm[j] - m2) * ((const vf4*)(pball + (size_t)j * PART_STRIDE + 16))[t];
    ((vf4*)(out_ctx + (size_t)b * DOUT))[t] = c * inv_l;

    float* arow = raw_scores + (size_t)b * SS;
#pragma unroll
    for (int k = 0; k < 4; ++k) {
      vf4 v = ((vf4*)arow)[t + 256 * k];
      v.x = __expf(v.x - m2) * inv_l;
      v.y = __expf(v.y - m2) * inv_l;
      v.z = __expf(v.z - m2) * inv_l;
      v.w = __expf(v.w - m2) * inv_l;
      ((vf4*)arow)[t + 256 * k] = v;
    }
  }
}

extern "C" void kernel_launch(void* const* d_in, const int* in_sizes, int n_in,
                              void* d_out, int out_size, void* d_ws, size_t ws_size,
                              hipStream_t stream) {
  const float* input = (const float*)d_in[0];   // [B, DIN]
  const float* hids  = (const float*)d_in[1];   // [B, S, DOUT]
  const float* seg   = (const float*)d_in[2];   // [B, S]
  const float* W     = (const float*)d_in[3];   // [DOUT, DIN]
  float* out = (float*)d_out;
  float* out_ctx  = out;                        // [B, DOUT]
  float* out_attn = out + (size_t)BB * DOUT;    // [B, S]

  float* x        = (float*)d_ws;               // [B, DOUT]
  float* partials = x + (size_t)BB * DOUT;      // [B, NCHUNK, PART_STRIDE]
  int*   cnt      = (int*)(partials + (size_t)BB * NCHUNK * PART_STRIDE);  // [B]

  proj_kernel<<<BB * 32, 256, 0, stream>>>(input, W, x, cnt);
  pass_kernel<<<BB * NCHUNK, 256, 0, stream>>>(hids, seg, x, out_attn, out_ctx, partials, cnt);
}

// Round 7
// 103.614 us; speedup vs baseline: 3.6294x; 3.6294x over previous
//
#include <hip/hip_runtime.h>
#include <math.h>

#define BB 32
#define SS 4096
#define DIN 1024
#define DOUT 1024
#define NCHUNK 32                          // s-chunks per batch row
#define ROWS_PER_BLOCK (SS / NCHUNK)       // 128
#define ROWS_PER_WAVE (ROWS_PER_BLOCK / 4) // 32
#define PART_STRIDE 1040                   // floats: [0]=m, [1]=l, [16..1039]=ctx[1024]
#define THR 25.0f                          // defer-max rescale threshold (e^25 safe in f32)

typedef float vf4 __attribute__((ext_vector_type(4)));

__device__ inline vf4 ntload4(const float* p) {
  return __builtin_nontemporal_load((const vf4*)p);
}

// ---------------- kernel 1: x[b,o] = sum_i input[b,i] * W[o,i] ----------------
// 1024 blocks (b, ochunk), 8 o-dots per wave, fully parallel (R5 form).
__global__ __launch_bounds__(256) void proj_kernel(const float* __restrict__ input,
                                                   const float* __restrict__ W,
                                                   float* __restrict__ x) {
  const int b = blockIdx.x >> 5;        // 32 o-chunks per b
  const int ochunk = blockIdx.x & 31;
  __shared__ float inp[DIN];
  const int t = threadIdx.x;
  ((vf4*)inp)[t] = ((const vf4*)(input + (size_t)b * DIN))[t];
  __syncthreads();
  const int wave = t >> 6, lane = t & 63;
#pragma unroll
  for (int j = 0; j < 8; ++j) {
    const int o = ochunk * 32 + wave * 8 + j;
    const vf4* wrow = (const vf4*)(W + (size_t)o * DIN);
    vf4 prod = (vf4)0.f;
#pragma unroll
    for (int k = 0; k < 4; ++k) prod += wrow[lane + 64 * k] * ((const vf4*)inp)[lane + 64 * k];
    float sum = prod.x + prod.y + prod.z + prod.w;
#pragma unroll
    for (int off = 32; off; off >>= 1) sum += __shfl_down(sum, off);
    if (lane == 0) x[(size_t)b * DOUT + o] = sum;
  }
}

// ---- kernel 2: single pass over source_hids: scores + online softmax + ctx ----
// 2-row x 2-ahead pipeline (16KB in flight per wave), defer-max softmax.
__global__ __launch_bounds__(256) void pass_kernel(const float* __restrict__ hids,
                                                   const float* __restrict__ seg,
                                                   const float* __restrict__ x,
                                                   float* __restrict__ raw_scores,   // d_out attn region
                                                   float* __restrict__ partials) {
  const int b = blockIdx.x >> 5;        // 32 chunks per b
  const int chunk = blockIdx.x & 31;
  const int t = threadIdx.x;
  __shared__ float xs[DOUT];
  __shared__ float buf[4][DOUT];
  __shared__ float sbuf[ROWS_PER_BLOCK];
  __shared__ float wstat[8];            // M[0..3], l[4..7]
  ((vf4*)xs)[t] = ((const vf4*)(x + (size_t)b * DOUT))[t];
  __syncthreads();
  const int wave = t >> 6, lane = t & 63;
  vf4 xv[4];
#pragma unroll
  for (int k = 0; k < 4; ++k) xv[k] = ((const vf4*)xs)[lane + 64 * k];

  const int s0 = chunk * ROWS_PER_BLOCK + wave * ROWS_PER_WAVE;
  const float* base = hids + ((size_t)b * SS + s0) * (size_t)DOUT;
  const float* segb = seg + (size_t)b * SS + s0;

  // all 32 seg values for this wave in one coalesced load (lane&31 avoids OOB)
  const float segv = segb[lane & 31];

  // ---- 2-row pipeline, 2 rows ahead (4 rows / 16KB in flight per wave) ----
  vf4 h0[4], h1[4], n0[4], n1[4];
#pragma unroll
  for (int k = 0; k < 4; ++k) h0[k] = ntload4(base + (lane + 64 * k) * 4);
#pragma unroll
  for (int k = 0; k < 4; ++k) h1[k] = ntload4(base + DOUT + (lane + 64 * k) * 4);
#pragma unroll
  for (int k = 0; k < 4; ++k) n0[k] = ntload4(base + 2 * DOUT + (lane + 64 * k) * 4);
#pragma unroll
  for (int k = 0; k < 4; ++k) n1[k] = ntload4(base + 3 * DOUT + (lane + 64 * k) * 4);

  // prologue: row 0 sets reference M; row 1 defer-max update
  vf4 prod0 = h0[0] * xv[0] + h0[1] * xv[1] + h0[2] * xv[2] + h0[3] * xv[3];
  float dot0 = prod0.x + prod0.y + prod0.z + prod0.w;
  vf4 prod1 = h1[0] * xv[0] + h1[1] * xv[1] + h1[2] * xv[2] + h1[3] * xv[3];
  float dot1 = prod1.x + prod1.y + prod1.z + prod1.w;
#pragma unroll
  for (int off = 32; off; off >>= 1) { dot0 += __shfl_xor(dot0, off); dot1 += __shfl_xor(dot1, off); }

  float M = dot0 - 100.f * (1.f - __shfl(segv, 0));
  float l = 1.f;
  vf4 acc[4];
#pragma unroll
  for (int k = 0; k < 4; ++k) acc[k] = h0[k];
  if (lane == 0) sbuf[wave * ROWS_PER_WAVE] = M;

  {
    const float score = dot1 - 100.f * (1.f - __shfl(segv, 1));
    if (lane == 0) sbuf[wave * ROWS_PER_WAVE + 1] = score;
    float p;
    if (__builtin_expect(score > M + THR, 0)) {
      const float corr = __expf(M - score);
      l *= corr;
#pragma unroll
      for (int k = 0; k < 4; ++k) acc[k] *= corr;
      M = score; p = 1.f;
    } else p = __expf(score - M);
    l += p;
#pragma unroll
    for (int k = 0; k < 4; ++k) acc[k] += p * h1[k];
  }

  // steady state: iteration rr processes rows 2rr, 2rr+1; prefetches 2rr+2, 2rr+3
#pragma unroll 2
  for (int rr = 1; rr < ROWS_PER_WAVE / 2; ++rr) {
#pragma unroll
    for (int k = 0; k < 4; ++k) { h0[k] = n0[k]; h1[k] = n1[k]; }
    if (rr + 1 < ROWS_PER_WAVE / 2) {
      const float* pb0 = base + (size_t)(2 * rr + 2) * DOUT;
      const float* pb1 = base + (size_t)(2 * rr + 3) * DOUT;
#pragma unroll
      for (int k = 0; k < 4; ++k) n0[k] = ntload4(pb0 + (lane + 64 * k) * 4);
#pragma unroll
      for (int k = 0; k < 4; ++k) n1[k] = ntload4(pb1 + (lane + 64 * k) * 4);
    }

    vf4 pa = h0[0] * xv[0] + h0[1] * xv[1] + h0[2] * xv[2] + h0[3] * xv[3];
    vf4 pbv = h1[0] * xv[0] + h1[1] * xv[1] + h1[2] * xv[2] + h1[3] * xv[3];
    float da = pa.x + pa.y + pa.z + pa.w;
    float db = pbv.x + pbv.y + pbv.z + pbv.w;
#pragma unroll
    for (int off = 32; off; off >>= 1) { da += __shfl_xor(da, off); db += __shfl_xor(db, off); }

    const float sa = da - 100.f * (1.f - __shfl(segv, 2 * rr));
    const float sb = db - 100.f * (1.f - __shfl(segv, 2 * rr + 1));
    if (lane == 0) {
      sbuf[wave * ROWS_PER_WAVE + 2 * rr] = sa;
      sbuf[wave * ROWS_PER_WAVE + 2 * rr + 1] = sb;
    }

    float p;
    if (__builtin_expect(sa > M + THR, 0)) {
      const float corr = __expf(M - sa);
      l *= corr;
#pragma unroll
      for (int k = 0; k < 4; ++k) acc[k] *= corr;
      M = sa; p = 1.f;
    } else p = __expf(sa - M);
    l += p;
#pragma unroll
    for (int k = 0; k < 4; ++k) acc[k] += p * h0[k];

    if (__builtin_expect(sb > M + THR, 0)) {
      const float corr = __expf(M - sb);
      l *= corr;
#pragma unroll
      for (int k = 0; k < 4; ++k) acc[k] *= corr;
      M = sb; p = 1.f;
    } else p = __expf(sb - M);
    l += p;
#pragma unroll
    for (int k = 0; k < 4; ++k) acc[k] += p * h1[k];
  }

  // ---- block-level combine of the 4 waves ----
  if (lane == 0) { wstat[wave] = M; wstat[4 + wave] = l; }
  __syncthreads();
  const float mb = fmaxf(fmaxf(wstat[0], wstat[1]), fmaxf(wstat[2], wstat[3]));
  const float scale = __expf(M - mb);     // per-wave scale to common reference
#pragma unroll
  for (int k = 0; k < 4; ++k)
    ((vf4*)buf[wave])[lane + 64 * k] = acc[k] * scale;
  __syncthreads();

  // coalesced raw-score write (one block: 128 contiguous floats)
  if (t < ROWS_PER_BLOCK)
    raw_scores[(size_t)b * SS + chunk * ROWS_PER_BLOCK + t] = sbuf[t];

  float* part = partials + ((size_t)b * NCHUNK + chunk) * PART_STRIDE;
  vf4 v0 = ((const vf4*)buf[0])[t];
  vf4 v1 = ((const vf4*)buf[1])[t];
  vf4 v2 = ((const vf4*)buf[2])[t];
  vf4 v3 = ((const vf4*)buf[3])[t];
  ((vf4*)(part + 16))[t] = (v0 + v1) + (v2 + v3);
  if (t == 0) {
    const float lb = wstat[4] * __expf(wstat[0] - mb) + wstat[5] * __expf(wstat[1] - mb) +
                     wstat[6] * __expf(wstat[2] - mb) + wstat[7] * __expf(wstat[3] - mb);
    part[0] = mb;
    part[1] = lb;
  }
}

// ---- kernel 3: merge partials -> ctx out; normalize attn. 8 blocks per b ----
__global__ __launch_bounds__(128) void combine_kernel(const float* __restrict__ partials,
                                                      float* __restrict__ out_ctx,
                                                      float* __restrict__ out_attn) {
  const int b = blockIdx.x >> 3;
  const int part = blockIdx.x & 7;
  const int t = threadIdx.x;            // 0..127
  const float* pb = partials + (size_t)b * NCHUNK * PART_STRIDE;

  __shared__ float sm[NCHUNK], sl[NCHUNK];
  if (t < NCHUNK) {
    sm[t] = pb[(size_t)t * PART_STRIDE];
    sl[t] = pb[(size_t)t * PART_STRIDE + 1];
  }
  __syncthreads();

  float m = -INFINITY;
#pragma unroll
  for (int j = 0; j < NCHUNK; ++j) m = fmaxf(m, sm[j]);
  float l = 0.f;
#pragma unroll
  for (int j = 0; j < NCHUNK; ++j) l += sl[j] * __expf(sm[j] - m);
  const float inv_l = 1.f / l;

  // this block's 128 ctx elements
  float c = 0.f;
#pragma unroll 8
  for (int j = 0; j < NCHUNK; ++j)
    c += __expf(sm[j] - m) * pb[(size_t)j * PART_STRIDE + 16 + part * 128 + t];
  out_ctx[(size_t)b * DOUT + part * 128 + t] = c * inv_l;

  // this block's 512 attn scores (as 128 float4)
  float* arow = out_attn + (size_t)b * SS + part * 512;
  float4 v = ((float4*)arow)[t];
  v.x = __expf(v.x - m) * inv_l;
  v.y = __expf(v.y - m) * inv_l;
  v.z = __expf(v.z - m) * inv_l;
  v.w = __expf(v.w - m) * inv_l;
  ((float4*)arow)[t] = v;
}

extern "C" void kernel_launch(void* const* d_in, const int* in_sizes, int n_in,
                              void* d_out, int out_size, void* d_ws, size_t ws_size,
                              hipStream_t stream) {
  const float* input = (const float*)d_in[0];   // [B, DIN]
  const float* hids  = (const float*)d_in[1];   // [B, S, DOUT]
  const float* seg   = (const float*)d_in[2];   // [B, S]
  const float* W     = (const float*)d_in[3];   // [DOUT, DIN]
  float* out = (float*)d_out;
  float* out_ctx  = out;                        // [B, DOUT]
  float* out_attn = out + (size_t)BB * DOUT;    // [B, S]

  float* x        = (float*)d_ws;               // [B, DOUT]
  float* partials = x + (size_t)BB * DOUT;      // [B, NCHUNK, PART_STRIDE]

  proj_kernel<<<BB * 32, 256, 0, stream>>>(input, W, x);
  pass_kernel<<<BB * NCHUNK, 256, 0, stream>>>(hids, seg, x, out_attn, partials);
  combine_kernel<<<BB * 8, 128, 0, stream>>>(partials, out_ctx, out_attn);
}

// Round 8
// 97.741 us; speedup vs baseline: 3.8475x; 1.0601x over previous
//
#include <hip/hip_runtime.h>
#include <math.h>

#define BB 32
#define SS 4096
#define DIN 1024
#define DOUT 1024
#define NCHUNK 32                          // s-chunks per batch row
#define ROWS_PER_BLOCK (SS / NCHUNK)       // 128
#define ROWS_PER_WAVE (ROWS_PER_BLOCK / 4) // 32
#define PART_STRIDE 1040                   // floats: [0]=m, [1]=l, [16..1039]=ctx[1024]
#define THR 25.0f                          // defer-max rescale threshold (e^25 safe in f32)

typedef float vf4 __attribute__((ext_vector_type(4)));

__device__ inline vf4 ntload4(const float* p) {
  return __builtin_nontemporal_load((const vf4*)p);
}

// ---------------- kernel 1: x[b,o] = sum_i input[b,i] * W[o,i] ----------------
// 1024 blocks (b, ochunk), 8 o-dots per wave, fully parallel.
__global__ __launch_bounds__(256) void proj_kernel(const float* __restrict__ input,
                                                   const float* __restrict__ W,
                                                   float* __restrict__ x) {
  const int b = blockIdx.x >> 5;        // 32 o-chunks per b
  const int ochunk = blockIdx.x & 31;
  __shared__ float inp[DIN];
  const int t = threadIdx.x;
  ((vf4*)inp)[t] = ((const vf4*)(input + (size_t)b * DIN))[t];
  __syncthreads();
  const int wave = t >> 6, lane = t & 63;
#pragma unroll
  for (int j = 0; j < 8; ++j) {
    const int o = ochunk * 32 + wave * 8 + j;
    const vf4* wrow = (const vf4*)(W + (size_t)o * DIN);
    vf4 prod = (vf4)0.f;
#pragma unroll
    for (int k = 0; k < 4; ++k) prod += wrow[lane + 64 * k] * ((const vf4*)inp)[lane + 64 * k];
    float sum = prod.x + prod.y + prod.z + prod.w;
#pragma unroll
    for (int off = 32; off; off >>= 1) sum += __shfl_down(sum, off);
    if (lane == 0) x[(size_t)b * DOUT + o] = sum;
  }
}

// ---- kernel 2: single pass over source_hids: scores + online softmax + ctx ----
// Wave-INTERLEAVED rows: wave w owns rows {w, w+4, ...} so the block's 4 waves
// march contiguously through the 512KB chunk (compact HBM stream front).
__global__ __launch_bounds__(256) void pass_kernel(const float* __restrict__ hids,
                                                   const float* __restrict__ seg,
                                                   const float* __restrict__ x,
                                                   float* __restrict__ raw_scores,   // d_out attn region
                                                   float* __restrict__ partials) {
  const int b = blockIdx.x >> 5;        // 32 chunks per b
  const int chunk = blockIdx.x & 31;
  const int t = threadIdx.x;
  __shared__ float xs[DOUT];
  __shared__ float buf[4][DOUT];
  __shared__ float sbuf[ROWS_PER_BLOCK];
  __shared__ float wstat[8];            // M[0..3], l[4..7]
  ((vf4*)xs)[t] = ((const vf4*)(x + (size_t)b * DOUT))[t];
  __syncthreads();
  const int wave = t >> 6, lane = t & 63;
  vf4 xv[4];
#pragma unroll
  for (int k = 0; k < 4; ++k) xv[k] = ((const vf4*)xs)[lane + 64 * k];

  const int s0 = chunk * ROWS_PER_BLOCK;          // block's first row
  const float* baseb = hids + ((size_t)b * SS + s0) * (size_t)DOUT;
  const float* basew = baseb + (size_t)wave * DOUT;   // wave's row r is basew + 4r*DOUT
  const float* segb = seg + (size_t)b * SS + s0;

  // wave's 32 seg values (rows wave+4r): stride-4 gather, one load
  const float segv = segb[4 * (lane & 31) + wave];

  // ---- 2-row pipeline, 2 rows ahead; wave-local row r = global row 4r+wave ----
  vf4 h0[4], h1[4], n0[4], n1[4];
#pragma unroll
  for (int k = 0; k < 4; ++k) h0[k] = ntload4(basew + (lane + 64 * k) * 4);
#pragma unroll
  for (int k = 0; k < 4; ++k) h1[k] = ntload4(basew + (size_t)4 * DOUT + (lane + 64 * k) * 4);
#pragma unroll
  for (int k = 0; k < 4; ++k) n0[k] = ntload4(basew + (size_t)8 * DOUT + (lane + 64 * k) * 4);
#pragma unroll
  for (int k = 0; k < 4; ++k) n1[k] = ntload4(basew + (size_t)12 * DOUT + (lane + 64 * k) * 4);

  // prologue: wave-local row 0 sets reference M; row 1 defer-max update
  vf4 prod0 = h0[0] * xv[0] + h0[1] * xv[1] + h0[2] * xv[2] + h0[3] * xv[3];
  float dot0 = prod0.x + prod0.y + prod0.z + prod0.w;
  vf4 prod1 = h1[0] * xv[0] + h1[1] * xv[1] + h1[2] * xv[2] + h1[3] * xv[3];
  float dot1 = prod1.x + prod1.y + prod1.z + prod1.w;
#pragma unroll
  for (int off = 32; off; off >>= 1) { dot0 += __shfl_xor(dot0, off); dot1 += __shfl_xor(dot1, off); }

  float M = dot0 - 100.f * (1.f - __shfl(segv, 0));
  float l = 1.f;
  vf4 acc[4];
#pragma unroll
  for (int k = 0; k < 4; ++k) acc[k] = h0[k];
  if (lane == 0) sbuf[wave] = M;                  // global row = wave

  {
    const float score = dot1 - 100.f * (1.f - __shfl(segv, 1));
    if (lane == 0) sbuf[4 + wave] = score;        // global row = 4+wave
    float p;
    if (__builtin_expect(score > M + THR, 0)) {
      const float corr = __expf(M - score);
      l *= corr;
#pragma unroll
      for (int k = 0; k < 4; ++k) acc[k] *= corr;
      M = score; p = 1.f;
    } else p = __expf(score - M);
    l += p;
#pragma unroll
    for (int k = 0; k < 4; ++k) acc[k] += p * h1[k];
  }

  // steady state: iter rr processes wave-local rows 2rr, 2rr+1; prefetch 2rr+2, 2rr+3
#pragma unroll 2
  for (int rr = 1; rr < ROWS_PER_WAVE / 2; ++rr) {
#pragma unroll
    for (int k = 0; k < 4; ++k) { h0[k] = n0[k]; h1[k] = n1[k]; }
    if (rr + 1 < ROWS_PER_WAVE / 2) {
      const float* pb0 = basew + (size_t)(8 * rr + 8) * DOUT;
      const float* pb1 = basew + (size_t)(8 * rr + 12) * DOUT;
#pragma unroll
      for (int k = 0; k < 4; ++k) n0[k] = ntload4(pb0 + (lane + 64 * k) * 4);
#pragma unroll
      for (int k = 0; k < 4; ++k) n1[k] = ntload4(pb1 + (lane + 64 * k) * 4);
    }

    vf4 pa = h0[0] * xv[0] + h0[1] * xv[1] + h0[2] * xv[2] + h0[3] * xv[3];
    vf4 pbv = h1[0] * xv[0] + h1[1] * xv[1] + h1[2] * xv[2] + h1[3] * xv[3];
    float da = pa.x + pa.y + pa.z + pa.w;
    float db = pbv.x + pbv.y + pbv.z + pbv.w;
#pragma unroll
    for (int off = 32; off; off >>= 1) { da += __shfl_xor(da, off); db += __shfl_xor(db, off); }

    const float sa = da - 100.f * (1.f - __shfl(segv, 2 * rr));
    const float sb = db - 100.f * (1.f - __shfl(segv, 2 * rr + 1));
    if (lane == 0) {
      sbuf[4 * (2 * rr) + wave] = sa;
      sbuf[4 * (2 * rr + 1) + wave] = sb;
    }

    float p;
    if (__builtin_expect(sa > M + THR, 0)) {
      const float corr = __expf(M - sa);
      l *= corr;
#pragma unroll
      for (int k = 0; k < 4; ++k) acc[k] *= corr;
      M = sa; p = 1.f;
    } else p = __expf(sa - M);
    l += p;
#pragma unroll
    for (int k = 0; k < 4; ++k) acc[k] += p * h0[k];

    if (__builtin_expect(sb > M + THR, 0)) {
      const float corr = __expf(M - sb);
      l *= corr;
#pragma unroll
      for (int k = 0; k < 4; ++k) acc[k] *= corr;
      M = sb; p = 1.f;
    } else p = __expf(sb - M);
    l += p;
#pragma unroll
    for (int k = 0; k < 4; ++k) acc[k] += p * h1[k];
  }

  // ---- block-level combine of the 4 waves ----
  if (lane == 0) { wstat[wave] = M; wstat[4 + wave] = l; }
  __syncthreads();
  const float mb = fmaxf(fmaxf(wstat[0], wstat[1]), fmaxf(wstat[2], wstat[3]));
  const float scale = __expf(M - mb);     // per-wave scale to common reference
#pragma unroll
  for (int k = 0; k < 4; ++k)
    ((vf4*)buf[wave])[lane + 64 * k] = acc[k] * scale;
  __syncthreads();

  // coalesced raw-score write (one block: 128 contiguous floats)
  if (t < ROWS_PER_BLOCK)
    raw_scores[(size_t)b * SS + chunk * ROWS_PER_BLOCK + t] = sbuf[t];

  float* part = partials + ((size_t)b * NCHUNK + chunk) * PART_STRIDE;
  vf4 v0 = ((const vf4*)buf[0])[t];
  vf4 v1 = ((const vf4*)buf[1])[t];
  vf4 v2 = ((const vf4*)buf[2])[t];
  vf4 v3 = ((const vf4*)buf[3])[t];
  ((vf4*)(part + 16))[t] = (v0 + v1) + (v2 + v3);
  if (t == 0) {
    const float lb = wstat[4] * __expf(wstat[0] - mb) + wstat[5] * __expf(wstat[1] - mb) +
                     wstat[6] * __expf(wstat[2] - mb) + wstat[7] * __expf(wstat[3] - mb);
    part[0] = mb;
    part[1] = lb;
  }
}

// ---- kernel 3: merge partials -> ctx out; normalize attn. 8 blocks per b ----
__global__ __launch_bounds__(128) void combine_kernel(const float* __restrict__ partials,
                                                      float* __restrict__ out_ctx,
                                                      float* __restrict__ out_attn) {
  const int b = blockIdx.x >> 3;
  const int part = blockIdx.x & 7;
  const int t = threadIdx.x;            // 0..127
  const float* pb = partials + (size_t)b * NCHUNK * PART_STRIDE;

  __shared__ float sm[NCHUNK], sl[NCHUNK];
  if (t < NCHUNK) {
    sm[t] = pb[(size_t)t * PART_STRIDE];
    sl[t] = pb[(size_t)t * PART_STRIDE + 1];
  }
  __syncthreads();

  float m = -INFINITY;
#pragma unroll
  for (int j = 0; j < NCHUNK; ++j) m = fmaxf(m, sm[j]);
  float l = 0.f;
#pragma unroll
  for (int j = 0; j < NCHUNK; ++j) l += sl[j] * __expf(sm[j] - m);
  const float inv_l = 1.f / l;

  // this block's 128 ctx elements
  float c = 0.f;
#pragma unroll 8
  for (int j = 0; j < NCHUNK; ++j)
    c += __expf(sm[j] - m) * pb[(size_t)j * PART_STRIDE + 16 + part * 128 + t];
  out_ctx[(size_t)b * DOUT + part * 128 + t] = c * inv_l;

  // this block's 512 attn scores (as 128 float4)
  float* arow = out_attn + (size_t)b * SS + part * 512;
  float4 v = ((float4*)arow)[t];
  v.x = __expf(v.x - m) * inv_l;
  v.y = __expf(v.y - m) * inv_l;
  v.z = __expf(v.z - m) * inv_l;
  v.w = __expf(v.w - m) * inv_l;
  ((float4*)arow)[t] = v;
}

extern "C" void kernel_launch(void* const* d_in, const int* in_sizes, int n_in,
                              void* d_out, int out_size, void* d_ws, size_t ws_size,
                              hipStream_t stream) {
  const float* input = (const float*)d_in[0];   // [B, DIN]
  const float* hids  = (const float*)d_in[1];   // [B, S, DOUT]
  const float* seg   = (const float*)d_in[2];   // [B, S]
  const float* W     = (const float*)d_in[3];   // [DOUT, DIN]
  float* out = (float*)d_out;
  float* out_ctx  = out;                        // [B, DOUT]
  float* out_attn = out + (size_t)BB * DOUT;    // [B, S]

  float* x        = (float*)d_ws;               // [B, DOUT]
  float* partials = x + (size_t)BB * DOUT;      // [B, NCHUNK, PART_STRIDE]

  proj_kernel<<<BB * 32, 256, 0, stream>>>(input, W, x);
  pass_kernel<<<BB * NCHUNK, 256, 0, stream>>>(hids, seg, x, out_attn, partials);
  combine_kernel<<<BB * 8, 128, 0, stream>>>(partials, out_ctx, out_attn);
}

// Round 9
// 94.086 us; speedup vs baseline: 3.9970x; 1.0388x over previous
//
#include <hip/hip_runtime.h>
#include <math.h>

#define BB 32
#define SS 4096
#define DIN 1024
#define DOUT 1024
#define NCHUNK 16                          // s-chunks per batch row (1MB per block)
#define ROWS_PER_BLOCK (SS / NCHUNK)       // 256
#define ROWS_PER_WAVE (ROWS_PER_BLOCK / 4) // 64
#define PART_STRIDE 1040                   // floats: [0]=m, [1]=l, [16..1039]=ctx[1024]
#define THR 25.0f                          // defer-max rescale threshold (e^25 safe in f32)

typedef float vf4 __attribute__((ext_vector_type(4)));

__device__ inline vf4 ntload4(const float* p) {
  return __builtin_nontemporal_load((const vf4*)p);
}

// ---------------- kernel 1: x[b,o] = sum_i input[b,i] * W[o,i] ----------------
// 1024 blocks (b, ochunk), 8 o-dots per wave, fully parallel.
__global__ __launch_bounds__(256) void proj_kernel(const float* __restrict__ input,
                                                   const float* __restrict__ W,
                                                   float* __restrict__ x) {
  const int b = blockIdx.x >> 5;        // 32 o-chunks per b
  const int ochunk = blockIdx.x & 31;
  __shared__ float inp[DIN];
  const int t = threadIdx.x;
  ((vf4*)inp)[t] = ((const vf4*)(input + (size_t)b * DIN))[t];
  __syncthreads();
  const int wave = t >> 6, lane = t & 63;
#pragma unroll
  for (int j = 0; j < 8; ++j) {
    const int o = ochunk * 32 + wave * 8 + j;
    const vf4* wrow = (const vf4*)(W + (size_t)o * DIN);
    vf4 prod = (vf4)0.f;
#pragma unroll
    for (int k = 0; k < 4; ++k) prod += wrow[lane + 64 * k] * ((const vf4*)inp)[lane + 64 * k];
    float sum = prod.x + prod.y + prod.z + prod.w;
#pragma unroll
    for (int off = 32; off; off >>= 1) sum += __shfl_down(sum, off);
    if (lane == 0) x[(size_t)b * DOUT + o] = sum;
  }
}

// ---- kernel 2: single pass over source_hids: scores + online softmax + ctx ----
// Wave-interleaved rows (wave w owns global rows 4r+w): compact HBM stream
// front per block; 512 blocks total (2 resident/CU) halves grid-wide fronts.
__global__ __launch_bounds__(256) void pass_kernel(const float* __restrict__ hids,
                                                   const float* __restrict__ seg,
                                                   const float* __restrict__ x,
                                                   float* __restrict__ raw_scores,   // d_out attn region
                                                   float* __restrict__ partials) {
  const int b = blockIdx.x >> 4;        // 16 chunks per b
  const int chunk = blockIdx.x & 15;
  const int t = threadIdx.x;
  __shared__ float xs[DOUT];
  __shared__ float buf[4][DOUT];
  __shared__ float sbuf[ROWS_PER_BLOCK];
  __shared__ float wstat[8];            // M[0..3], l[4..7]
  ((vf4*)xs)[t] = ((const vf4*)(x + (size_t)b * DOUT))[t];
  __syncthreads();
  const int wave = t >> 6, lane = t & 63;
  vf4 xv[4];
#pragma unroll
  for (int k = 0; k < 4; ++k) xv[k] = ((const vf4*)xs)[lane + 64 * k];

  const int s0 = chunk * ROWS_PER_BLOCK;              // block's first row
  const float* baseb = hids + ((size_t)b * SS + s0) * (size_t)DOUT;
  const float* basew = baseb + (size_t)wave * DOUT;   // wave's row r is basew + 4r*DOUT
  const float* segb = seg + (size_t)b * SS + s0;

  // wave's 64 seg values (global rows 4*lane+wave): one stride-4 gather
  const float segv = segb[4 * lane + wave];

  // ---- 2-row pipeline, 2 rows ahead; wave-local row r = global row 4r+wave ----
  vf4 h0[4], h1[4], n0[4], n1[4];
#pragma unroll
  for (int k = 0; k < 4; ++k) h0[k] = ntload4(basew + (lane + 64 * k) * 4);
#pragma unroll
  for (int k = 0; k < 4; ++k) h1[k] = ntload4(basew + (size_t)4 * DOUT + (lane + 64 * k) * 4);
#pragma unroll
  for (int k = 0; k < 4; ++k) n0[k] = ntload4(basew + (size_t)8 * DOUT + (lane + 64 * k) * 4);
#pragma unroll
  for (int k = 0; k < 4; ++k) n1[k] = ntload4(basew + (size_t)12 * DOUT + (lane + 64 * k) * 4);

  // prologue: wave-local row 0 sets reference M; row 1 defer-max update
  vf4 prod0 = h0[0] * xv[0] + h0[1] * xv[1] + h0[2] * xv[2] + h0[3] * xv[3];
  float dot0 = prod0.x + prod0.y + prod0.z + prod0.w;
  vf4 prod1 = h1[0] * xv[0] + h1[1] * xv[1] + h1[2] * xv[2] + h1[3] * xv[3];
  float dot1 = prod1.x + prod1.y + prod1.z + prod1.w;
#pragma unroll
  for (int off = 32; off; off >>= 1) { dot0 += __shfl_xor(dot0, off); dot1 += __shfl_xor(dot1, off); }

  float M = dot0 - 100.f * (1.f - __shfl(segv, 0));
  float l = 1.f;
  vf4 acc[4];
#pragma unroll
  for (int k = 0; k < 4; ++k) acc[k] = h0[k];
  if (lane == 0) sbuf[wave] = M;                  // global row = wave

  {
    const float score = dot1 - 100.f * (1.f - __shfl(segv, 1));
    if (lane == 0) sbuf[4 + wave] = score;        // global row = 4+wave
    float p;
    if (__builtin_expect(score > M + THR, 0)) {
      const float corr = __expf(M - score);
      l *= corr;
#pragma unroll
      for (int k = 0; k < 4; ++k) acc[k] *= corr;
      M = score; p = 1.f;
    } else p = __expf(score - M);
    l += p;
#pragma unroll
    for (int k = 0; k < 4; ++k) acc[k] += p * h1[k];
  }

  // steady state: iter rr processes wave-local rows 2rr, 2rr+1; prefetch 2rr+2, 2rr+3
#pragma unroll 2
  for (int rr = 1; rr < ROWS_PER_WAVE / 2; ++rr) {
#pragma unroll
    for (int k = 0; k < 4; ++k) { h0[k] = n0[k]; h1[k] = n1[k]; }
    if (rr + 1 < ROWS_PER_WAVE / 2) {
      const float* pb0 = basew + (size_t)(8 * rr + 8) * DOUT;
      const float* pb1 = basew + (size_t)(8 * rr + 12) * DOUT;
#pragma unroll
      for (int k = 0; k < 4; ++k) n0[k] = ntload4(pb0 + (lane + 64 * k) * 4);
#pragma unroll
      for (int k = 0; k < 4; ++k) n1[k] = ntload4(pb1 + (lane + 64 * k) * 4);
    }

    vf4 pa = h0[0] * xv[0] + h0[1] * xv[1] + h0[2] * xv[2] + h0[3] * xv[3];
    vf4 pbv = h1[0] * xv[0] + h1[1] * xv[1] + h1[2] * xv[2] + h1[3] * xv[3];
    float da = pa.x + pa.y + pa.z + pa.w;
    float db = pbv.x + pbv.y + pbv.z + pbv.w;
#pragma unroll
    for (int off = 32; off; off >>= 1) { da += __shfl_xor(da, off); db += __shfl_xor(db, off); }

    const float sa = da - 100.f * (1.f - __shfl(segv, 2 * rr));
    const float sb = db - 100.f * (1.f - __shfl(segv, 2 * rr + 1));
    if (lane == 0) {
      sbuf[4 * (2 * rr) + wave] = sa;
      sbuf[4 * (2 * rr + 1) + wave] = sb;
    }

    float p;
    if (__builtin_expect(sa > M + THR, 0)) {
      const float corr = __expf(M - sa);
      l *= corr;
#pragma unroll
      for (int k = 0; k < 4; ++k) acc[k] *= corr;
      M = sa; p = 1.f;
    } else p = __expf(sa - M);
    l += p;
#pragma unroll
    for (int k = 0; k < 4; ++k) acc[k] += p * h0[k];

    if (__builtin_expect(sb > M + THR, 0)) {
      const float corr = __expf(M - sb);
      l *= corr;
#pragma unroll
      for (int k = 0; k < 4; ++k) acc[k] *= corr;
      M = sb; p = 1.f;
    } else p = __expf(sb - M);
    l += p;
#pragma unroll
    for (int k = 0; k < 4; ++k) acc[k] += p * h1[k];
  }

  // ---- block-level combine of the 4 waves ----
  if (lane == 0) { wstat[wave] = M; wstat[4 + wave] = l; }
  __syncthreads();
  const float mb = fmaxf(fmaxf(wstat[0], wstat[1]), fmaxf(wstat[2], wstat[3]));
  const float scale = __expf(M - mb);     // per-wave scale to common reference
#pragma unroll
  for (int k = 0; k < 4; ++k)
    ((vf4*)buf[wave])[lane + 64 * k] = acc[k] * scale;
  __syncthreads();

  // coalesced raw-score write (256 contiguous floats)
  raw_scores[(size_t)b * SS + chunk * ROWS_PER_BLOCK + t] = sbuf[t];

  float* part = partials + ((size_t)b * NCHUNK + chunk) * PART_STRIDE;
  vf4 v0 = ((const vf4*)buf[0])[t];
  vf4 v1 = ((const vf4*)buf[1])[t];
  vf4 v2 = ((const vf4*)buf[2])[t];
  vf4 v3 = ((const vf4*)buf[3])[t];
  ((vf4*)(part + 16))[t] = (v0 + v1) + (v2 + v3);
  if (t == 0) {
    const float lb = wstat[4] * __expf(wstat[0] - mb) + wstat[5] * __expf(wstat[1] - mb) +
                     wstat[6] * __expf(wstat[2] - mb) + wstat[7] * __expf(wstat[3] - mb);
    part[0] = mb;
    part[1] = lb;
  }
}

// ---- kernel 3: merge partials -> ctx out; normalize attn. 8 blocks per b ----
__global__ __launch_bounds__(128) void combine_kernel(const float* __restrict__ partials,
                                                      float* __restrict__ out_ctx,
                                                      float* __restrict__ out_attn) {
  const int b = blockIdx.x >> 3;
  const int part = blockIdx.x & 7;
  const int t = threadIdx.x;            // 0..127
  const float* pb = partials + (size_t)b * NCHUNK * PART_STRIDE;

  __shared__ float sm[NCHUNK], sl[NCHUNK];
  if (t < NCHUNK) {
    sm[t] = pb[(size_t)t * PART_STRIDE];
    sl[t] = pb[(size_t)t * PART_STRIDE + 1];
  }
  __syncthreads();

  float m = -INFINITY;
#pragma unroll
  for (int j = 0; j < NCHUNK; ++j) m = fmaxf(m, sm[j]);
  float l = 0.f;
#pragma unroll
  for (int j = 0; j < NCHUNK; ++j) l += sl[j] * __expf(sm[j] - m);
  const float inv_l = 1.f / l;

  // this block's 128 ctx elements
  float c = 0.f;
#pragma unroll 8
  for (int j = 0; j < NCHUNK; ++j)
    c += __expf(sm[j] - m) * pb[(size_t)j * PART_STRIDE + 16 + part * 128 + t];
  out_ctx[(size_t)b * DOUT + part * 128 + t] = c * inv_l;

  // this block's 512 attn scores (as 128 float4)
  float* arow = out_attn + (size_t)b * SS + part * 512;
  float4 v = ((float4*)arow)[t];
  v.x = __expf(v.x - m) * inv_l;
  v.y = __expf(v.y - m) * inv_l;
  v.z = __expf(v.z - m) * inv_l;
  v.w = __expf(v.w - m) * inv_l;
  ((float4*)arow)[t] = v;
}

extern "C" void kernel_launch(void* const* d_in, const int* in_sizes, int n_in,
                              void* d_out, int out_size, void* d_ws, size_t ws_size,
                              hipStream_t stream) {
  const float* input = (const float*)d_in[0];   // [B, DIN]
  const float* hids  = (const float*)d_in[1];   // [B, S, DOUT]
  const float* seg   = (const float*)d_in[2];   // [B, S]
  const float* W     = (const float*)d_in[3];   // [DOUT, DIN]
  float* out = (float*)d_out;
  float* out_ctx  = out;                        // [B, DOUT]
  float* out_attn = out + (size_t)BB * DOUT;    // [B, S]

  float* x        = (float*)d_ws;               // [B, DOUT]
  float* partials = x + (size_t)BB * DOUT;      // [B, NCHUNK, PART_STRIDE]

  proj_kernel<<<BB * 32, 256, 0, stream>>>(input, W, x);
  pass_kernel<<<BB * NCHUNK, 256, 0, stream>>>(hids, seg, x, out_attn, partials);
  combine_kernel<<<BB * 8, 128, 0, stream>>>(partials, out_ctx, out_attn);
}

// Round 10
// 89.722 us; speedup vs baseline: 4.1914x; 1.0486x over previous
//
#include <hip/hip_runtime.h>
#include <math.h>

#define BB 32
#define SS 4096
#define DIN 1024
#define DOUT 1024
#define NCHUNK 8                           // s-chunks per batch row (2MB per block)
#define ROWS_PER_BLOCK (SS / NCHUNK)       // 512
#define ROWS_PER_WAVE (ROWS_PER_BLOCK / 4) // 128
#define PART_STRIDE 1040                   // floats: [0]=m, [1]=l, [16..1039]=ctx[1024]
#define THR 25.0f                          // defer-max rescale threshold (e^25 safe in f32)

typedef float vf4 __attribute__((ext_vector_type(4)));

__device__ inline vf4 ntload4(const float* p) {
  return __builtin_nontemporal_load((const vf4*)p);
}

// ---------------- kernel 1: x[b,o] = sum_i input[b,i] * W[o,i] ----------------
// 1024 blocks (b, ochunk), 8 o-dots per wave, fully parallel.
__global__ __launch_bounds__(256) void proj_kernel(const float* __restrict__ input,
                                                   const float* __restrict__ W,
                                                   float* __restrict__ x) {
  const int b = blockIdx.x >> 5;        // 32 o-chunks per b
  const int ochunk = blockIdx.x & 31;
  __shared__ float inp[DIN];
  const int t = threadIdx.x;
  ((vf4*)inp)[t] = ((const vf4*)(input + (size_t)b * DIN))[t];
  __syncthreads();
  const int wave = t >> 6, lane = t & 63;
#pragma unroll
  for (int j = 0; j < 8; ++j) {
    const int o = ochunk * 32 + wave * 8 + j;
    const vf4* wrow = (const vf4*)(W + (size_t)o * DIN);
    vf4 prod = (vf4)0.f;
#pragma unroll
    for (int k = 0; k < 4; ++k) prod += wrow[lane + 64 * k] * ((const vf4*)inp)[lane + 64 * k];
    float sum = prod.x + prod.y + prod.z + prod.w;
#pragma unroll
    for (int off = 32; off; off >>= 1) sum += __shfl_down(sum, off);
    if (lane == 0) x[(size_t)b * DOUT + o] = sum;
  }
}

// ---- kernel 2: single pass over source_hids: scores + online softmax + ctx ----
// Wave-interleaved rows (wave w owns global rows 4r+w); 256 blocks = 1/CU,
// 256 grid-wide HBM stream fronts of 2MB each.
__global__ __launch_bounds__(256) void pass_kernel(const float* __restrict__ hids,
                                                   const float* __restrict__ seg,
                                                   const float* __restrict__ x,
                                                   float* __restrict__ raw_scores,   // d_out attn region
                                                   float* __restrict__ partials) {
  const int b = blockIdx.x >> 3;        // 8 chunks per b
  const int chunk = blockIdx.x & 7;
  const int t = threadIdx.x;
  __shared__ float xs[DOUT];
  __shared__ float buf[4][DOUT];
  __shared__ float sbuf[ROWS_PER_BLOCK];
  __shared__ float wstat[8];            // M[0..3], l[4..7]
  ((vf4*)xs)[t] = ((const vf4*)(x + (size_t)b * DOUT))[t];
  __syncthreads();
  const int wave = t >> 6, lane = t & 63;
  vf4 xv[4];
#pragma unroll
  for (int k = 0; k < 4; ++k) xv[k] = ((const vf4*)xs)[lane + 64 * k];

  const int s0 = chunk * ROWS_PER_BLOCK;              // block's first row
  const float* baseb = hids + ((size_t)b * SS + s0) * (size_t)DOUT;
  const float* basew = baseb + (size_t)wave * DOUT;   // wave's row r is basew + 4r*DOUT
  const float* segb = seg + (size_t)b * SS + s0;

  // wave's 128 seg values (global rows 4r+wave, r=0..127): two stride-4 gathers
  const float segv0 = segb[4 * lane + wave];          // r = 0..63
  const float segv1 = segb[256 + 4 * lane + wave];    // r = 64..127

  // ---- 2-row pipeline, 2 rows ahead; wave-local row r = global row 4r+wave ----
  vf4 h0[4], h1[4], n0[4], n1[4];
#pragma unroll
  for (int k = 0; k < 4; ++k) h0[k] = ntload4(basew + (lane + 64 * k) * 4);
#pragma unroll
  for (int k = 0; k < 4; ++k) h1[k] = ntload4(basew + (size_t)4 * DOUT + (lane + 64 * k) * 4);
#pragma unroll
  for (int k = 0; k < 4; ++k) n0[k] = ntload4(basew + (size_t)8 * DOUT + (lane + 64 * k) * 4);
#pragma unroll
  for (int k = 0; k < 4; ++k) n1[k] = ntload4(basew + (size_t)12 * DOUT + (lane + 64 * k) * 4);

  // prologue: wave-local row 0 sets reference M; row 1 defer-max update
  vf4 prod0 = h0[0] * xv[0] + h0[1] * xv[1] + h0[2] * xv[2] + h0[3] * xv[3];
  float dot0 = prod0.x + prod0.y + prod0.z + prod0.w;
  vf4 prod1 = h1[0] * xv[0] + h1[1] * xv[1] + h1[2] * xv[2] + h1[3] * xv[3];
  float dot1 = prod1.x + prod1.y + prod1.z + prod1.w;
#pragma unroll
  for (int off = 32; off; off >>= 1) { dot0 += __shfl_xor(dot0, off); dot1 += __shfl_xor(dot1, off); }

  float M = dot0 - 100.f * (1.f - __shfl(segv0, 0));
  float l = 1.f;
  vf4 acc[4];
#pragma unroll
  for (int k = 0; k < 4; ++k) acc[k] = h0[k];
  if (lane == 0) sbuf[wave] = M;                  // global row = wave

  {
    const float score = dot1 - 100.f * (1.f - __shfl(segv0, 1));
    if (lane == 0) sbuf[4 + wave] = score;        // global row = 4+wave
    float p;
    if (__builtin_expect(score > M + THR, 0)) {
      const float corr = __expf(M - score);
      l *= corr;
#pragma unroll
      for (int k = 0; k < 4; ++k) acc[k] *= corr;
      M = score; p = 1.f;
    } else p = __expf(score - M);
    l += p;
#pragma unroll
    for (int k = 0; k < 4; ++k) acc[k] += p * h1[k];
  }

  // steady state: iter rr processes wave-local rows 2rr, 2rr+1; prefetch 2rr+2, 2rr+3
#pragma unroll 2
  for (int rr = 1; rr < ROWS_PER_WAVE / 2; ++rr) {
#pragma unroll
    for (int k = 0; k < 4; ++k) { h0[k] = n0[k]; h1[k] = n1[k]; }
    if (rr + 1 < ROWS_PER_WAVE / 2) {
      const float* pb0 = basew + (size_t)(8 * rr + 8) * DOUT;
      const float* pb1 = basew + (size_t)(8 * rr + 12) * DOUT;
#pragma unroll
      for (int k = 0; k < 4; ++k) n0[k] = ntload4(pb0 + (lane + 64 * k) * 4);
#pragma unroll
      for (int k = 0; k < 4; ++k) n1[k] = ntload4(pb1 + (lane + 64 * k) * 4);
    }

    vf4 pa = h0[0] * xv[0] + h0[1] * xv[1] + h0[2] * xv[2] + h0[3] * xv[3];
    vf4 pbv = h1[0] * xv[0] + h1[1] * xv[1] + h1[2] * xv[2] + h1[3] * xv[3];
    float da = pa.x + pa.y + pa.z + pa.w;
    float db = pbv.x + pbv.y + pbv.z + pbv.w;
#pragma unroll
    for (int off = 32; off; off >>= 1) { da += __shfl_xor(da, off); db += __shfl_xor(db, off); }

    const int ra = 2 * rr, rb = 2 * rr + 1;
    const float sega0 = __shfl(segv0, ra & 63), sega1 = __shfl(segv1, ra & 63);
    const float segb0 = __shfl(segv0, rb & 63), segb1 = __shfl(segv1, rb & 63);
    const float sa = da - 100.f * (1.f - (ra < 64 ? sega0 : sega1));
    const float sb = db - 100.f * (1.f - (rb < 64 ? segb0 : segb1));
    if (lane == 0) {
      sbuf[4 * ra + wave] = sa;
      sbuf[4 * rb + wave] = sb;
    }

    float p;
    if (__builtin_expect(sa > M + THR, 0)) {
      const float corr = __expf(M - sa);
      l *= corr;
#pragma unroll
      for (int k = 0; k < 4; ++k) acc[k] *= corr;
      M = sa; p = 1.f;
    } else p = __expf(sa - M);
    l += p;
#pragma unroll
    for (int k = 0; k < 4; ++k) acc[k] += p * h0[k];

    if (__builtin_expect(sb > M + THR, 0)) {
      const float corr = __expf(M - sb);
      l *= corr;
#pragma unroll
      for (int k = 0; k < 4; ++k) acc[k] *= corr;
      M = sb; p = 1.f;
    } else p = __expf(sb - M);
    l += p;
#pragma unroll
    for (int k = 0; k < 4; ++k) acc[k] += p * h1[k];
  }

  // ---- block-level combine of the 4 waves ----
  if (lane == 0) { wstat[wave] = M; wstat[4 + wave] = l; }
  __syncthreads();
  const float mb = fmaxf(fmaxf(wstat[0], wstat[1]), fmaxf(wstat[2], wstat[3]));
  const float scale = __expf(M - mb);     // per-wave scale to common reference
#pragma unroll
  for (int k = 0; k < 4; ++k)
    ((vf4*)buf[wave])[lane + 64 * k] = acc[k] * scale;
  __syncthreads();

  // coalesced raw-score write (512 contiguous floats by 256 threads)
#pragma unroll
  for (int k = 0; k < 2; ++k)
    raw_scores[(size_t)b * SS + chunk * ROWS_PER_BLOCK + t + 256 * k] = sbuf[t + 256 * k];

  float* part = partials + ((size_t)b * NCHUNK + chunk) * PART_STRIDE;
  vf4 v0 = ((const vf4*)buf[0])[t];
  vf4 v1 = ((const vf4*)buf[1])[t];
  vf4 v2 = ((const vf4*)buf[2])[t];
  vf4 v3 = ((const vf4*)buf[3])[t];
  ((vf4*)(part + 16))[t] = (v0 + v1) + (v2 + v3);
  if (t == 0) {
    const float lb = wstat[4] * __expf(wstat[0] - mb) + wstat[5] * __expf(wstat[1] - mb) +
                     wstat[6] * __expf(wstat[2] - mb) + wstat[7] * __expf(wstat[3] - mb);
    part[0] = mb;
    part[1] = lb;
  }
}

// ---- kernel 3: merge partials -> ctx out; normalize attn. 8 blocks per b ----
__global__ __launch_bounds__(128) void combine_kernel(const float* __restrict__ partials,
                                                      float* __restrict__ out_ctx,
                                                      float* __restrict__ out_attn) {
  const int b = blockIdx.x >> 3;
  const int part = blockIdx.x & 7;
  const int t = threadIdx.x;            // 0..127
  const float* pb = partials + (size_t)b * NCHUNK * PART_STRIDE;

  __shared__ float sm[NCHUNK], sl[NCHUNK];
  if (t < NCHUNK) {
    sm[t] = pb[(size_t)t * PART_STRIDE];
    sl[t] = pb[(size_t)t * PART_STRIDE + 1];
  }
  __syncthreads();

  float m = -INFINITY;
#pragma unroll
  for (int j = 0; j < NCHUNK; ++j) m = fmaxf(m, sm[j]);
  float l = 0.f;
#pragma unroll
  for (int j = 0; j < NCHUNK; ++j) l += sl[j] * __expf(sm[j] - m);
  const float inv_l = 1.f / l;

  // this block's 128 ctx elements
  float c = 0.f;
#pragma unroll
  for (int j = 0; j < NCHUNK; ++j)
    c += __expf(sm[j] - m) * pb[(size_t)j * PART_STRIDE + 16 + part * 128 + t];
  out_ctx[(size_t)b * DOUT + part * 128 + t] = c * inv_l;

  // this block's 512 attn scores (as 128 float4)
  float* arow = out_attn + (size_t)b * SS + part * 512;
  float4 v = ((float4*)arow)[t];
  v.x = __expf(v.x - m) * inv_l;
  v.y = __expf(v.y - m) * inv_l;
  v.z = __expf(v.z - m) * inv_l;
  v.w = __expf(v.w - m) * inv_l;
  ((float4*)arow)[t] = v;
}

extern "C" void kernel_launch(void* const* d_in, const int* in_sizes, int n_in,
                              void* d_out, int out_size, void* d_ws, size_t ws_size,
                              hipStream_t stream) {
  const float* input = (const float*)d_in[0];   // [B, DIN]
  const float* hids  = (const float*)d_in[1];   // [B, S, DOUT]
  const float* seg   = (const float*)d_in[2];   // [B, S]
  const float* W     = (const float*)d_in[3];   // [DOUT, DIN]
  float* out = (float*)d_out;
  float* out_ctx  = out;                        // [B, DOUT]
  float* out_attn = out + (size_t)BB * DOUT;    // [B, S]

  float* x        = (float*)d_ws;               // [B, DOUT]
  float* partials = x + (size_t)BB * DOUT;      // [B, NCHUNK, PART_STRIDE]

  proj_kernel<<<BB * 32, 256, 0, stream>>>(input, W, x);
  pass_kernel<<<BB * NCHUNK, 256, 0, stream>>>(hids, seg, x, out_attn, partials);
  combine_kernel<<<BB * 8, 128, 0, stream>>>(partials, out_ctx, out_attn);
}